// Round 15
// baseline (229.489 us; speedup 1.0000x reference)
//
#include <hip/hip_runtime.h>

#define N_NODES 100000
#define N_EDGES 1200000
#define NF 64

typedef __attribute__((ext_vector_type(8))) short short8;
typedef __attribute__((ext_vector_type(4))) float float4v;

__device__ __forceinline__ ushort f2bf(float f) {
    unsigned u = __float_as_uint(f);
    return (ushort)((u + 0x7FFF + ((u >> 16) & 1)) >> 16);  // RNE
}

// binning: bin = node >> 9, 196 bins of 512 nodes, fixed capacity per bin
#define NBINS 196
#define CAP 10240                // per-node pad-to-16: E[usage] ~9000, >7 sigma margin
#define EPB 2560
#define NBLK 469                 // ceil(1200000/2560)

// ---------------- workspace layout (bytes), flat, no overlays (~51 MB of 268 MB)
#define OFF_CNT    0             // int[100000]
#define OFF_ENDP   400128        // int[100000]
#define OFF_DINV   800256        // float[100000]
#define OFF_CUR    1200384       // int[392] global bin cursors
#define OFF_PKW    1202048       // ushort[2*1024*8] = 32 KB packed B-fragments
#define OFF_SRCS   1234816       // int[196*10240]    = 8.03 MB (final, dst-binned)
#define OFF_NRMS   9262976       // ushort[196*10240] = 4.01 MB
#define OFF_SBIN   13277056      // ushort[196*10240] staging
#define OFF_DBIN   17291136      // int[196*10240]    staging
#define OFF_EMBBF  25319296      // ushort[6.4M] = 12.8 MB
#define OFF_HBF    38119296      // ushort[6.4M] = 12.8 MB -> ends 50,919,296

// blocks 0-7: pack W into B-fragment order; block 8: init cursors;
// blocks 9+: emb f32 -> bf16
__global__ __launch_bounds__(256) void prep(const float* __restrict__ W10,
                                            const float* __restrict__ W11,
                                            const float* __restrict__ W20,
                                            const float* __restrict__ W21,
                                            ushort* __restrict__ pk,
                                            int* __restrict__ cur,
                                            const float* __restrict__ emb,
                                            ushort* __restrict__ emb_bf) {
    int b = blockIdx.x;
    int t = threadIdx.x;
    if (b < 8) {
        int idx = b * 256 + t;   // [0, 2048)
        int layer = idx >> 10;
        int rest = idx & 1023;
        int f = rest >> 6, L = rest & 63;
        int n = (f & 3) * 16 + (L & 15);
        int kb = (f >> 2) * 32 + ((L >> 4) << 3);
#pragma unroll
        for (int j = 0; j < 8; ++j) {
            int k = kb + j;
            const float* W = layer ? ((k < 64) ? W20 : W21) : ((k < 64) ? W10 : W11);
            pk[idx * 8 + j] = f2bf(W[(k & 63) * 64 + n]);
        }
    } else if (b == 8) {
        for (int i = t; i < 2 * NBINS; i += 256)
            cur[i] = (i < NBINS ? i : i - NBINS) * CAP;
    } else {
        int i = ((b - 9) * 256 + t) * 8;
        float4 v0 = *(const float4*)(emb + i);
        float4 v1 = *(const float4*)(emb + i + 4);
        uint4 o;
        o.x = (uint)f2bf(v0.x) | ((uint)f2bf(v0.y) << 16);
        o.y = (uint)f2bf(v0.z) | ((uint)f2bf(v0.w) << 16);
        o.z = (uint)f2bf(v1.x) | ((uint)f2bf(v1.y) << 16);
        o.w = (uint)f2bf(v1.z) | ((uint)f2bf(v1.w) << 16);
        *(uint4*)(emb_bf + i) = o;
    }
}

// single-pass binned counting sort: LDS hist -> chunk reservation -> scatter.
__global__ __launch_bounds__(256) void binsort(const int* __restrict__ row,
                                               const int* __restrict__ col,
                                               int* __restrict__ cur,
                                               ushort* __restrict__ sbinned,
                                               int* __restrict__ dbinned) {
    __shared__ int2 ecache[EPB];               // 20 KB
    __shared__ int sh[NBINS], dh[NBINS];
    __shared__ int sbase[NBINS], dbase[NBINS];
    int t = threadIdx.x;
    if (t < NBINS) { sh[t] = 0; dh[t] = 0; }
    __syncthreads();
    int base = blockIdx.x * EPB;
    for (int k = 0; k < EPB / 256; ++k) {
        int e = base + k * 256 + t;
        int s = -1, d = -1;
        if (e < N_EDGES) { s = row[e]; d = col[e]; }
        ecache[k * 256 + t] = make_int2(s, d);
        if (s >= 0 && s != d) {
            atomicAdd(&sh[s >> 9], 1);
            atomicAdd(&dh[d >> 9], 1);
        }
    }
    __syncthreads();
    if (t < NBINS) {
        sbase[t] = atomicAdd(&cur[t], sh[t]);
        dbase[t] = atomicAdd(&cur[NBINS + t], dh[t]);
    }
    __syncthreads();
    for (int k = 0; k < EPB / 256; ++k) {
        int2 p = ecache[k * 256 + t];
        int s = p.x, d = p.y;
        if (s >= 0 && s != d) {
            int ss = atomicAdd(&sbase[s >> 9], 1);
            sbinned[ss] = (ushort)(s & 511);
            int ds = atomicAdd(&dbase[d >> 9], 1);
            dbinned[ds] = (s << 9) | (d & 511);
        }
    }
}

// per src-bin per-node histogram -> dinv (512 threads, 1 node/thread)
__global__ __launch_bounds__(512) void binD1(const ushort* __restrict__ sbinned,
                                             const int* __restrict__ cur,
                                             float* __restrict__ dinv) {
    __shared__ int hist[512];
    int t = threadIdx.x;
    hist[t] = 0;
    __syncthreads();
    int b = blockIdx.x;
    int start = b * CAP;
    int end = cur[b];
    for (int i = start + t; i < end; i += 512)
        atomicAdd(&hist[sbinned[i]], 1);
    __syncthreads();
    int n0 = (b << 9) + t;
    if (n0 < N_NODES) dinv[n0] = hist[t] ? rsqrtf((float)hist[t]) : 0.0f;
}

// per dst-bin: hist + scan of 16-aligned counts -> cnt/endp + srcs/nrms scatter.
// Per-node segments padded to x16 with ZERO norms -> layer needs no masking.
__global__ __launch_bounds__(512) void binD2(const int* __restrict__ dbinned,
                                             const int* __restrict__ cur,
                                             const float* __restrict__ dinv,
                                             int* __restrict__ cnt,
                                             int* __restrict__ endp,
                                             int* __restrict__ srcs,
                                             ushort* __restrict__ nrms) {
    __shared__ int hist[512];
    __shared__ int lcur[512];
    int t = threadIdx.x;
    hist[t] = 0;
    __syncthreads();
    int b = blockIdx.x;
    int start = b * CAP;
    int end = cur[NBINS + b];
    for (int i = start + t; i < end; i += 512)
        atomicAdd(&hist[dbinned[i] & 511], 1);
    __syncthreads();
    int o0 = hist[t];
    int A0 = (o0 + 15) & ~15;   // pad-to-16
    __syncthreads();
    hist[t] = A0;
    __syncthreads();
    for (int off = 1; off < 512; off <<= 1) {
        int v = (t >= off) ? hist[t - off] : 0;
        __syncthreads();
        hist[t] += v;
        __syncthreads();
    }
    int e0 = hist[t] - A0;   // exclusive (16-aligned)
    lcur[t] = start + e0;
    int n0 = (b << 9) + t;
    if (n0 < N_NODES) { cnt[n0] = o0; endp[n0] = start + e0 + o0; }
    __syncthreads();
    for (int i = start + t; i < end; i += 512) {
        int p = dbinned[i];
        int s = p >> 9, dl = p & 511;
        int slot = atomicAdd(&lcur[dl], 1);
        srcs[slot] = s;
        nrms[slot] = f2bf(-dinv[s] * dinv[(b << 9) + dl]);
    }
    __syncthreads();
    // zero-fill per-node pad slots (norm=0 -> contributes nothing; srcs=0 valid)
    for (int k = o0; k < A0; ++k) { srcs[start + e0 + k] = 0; nrms[start + e0 + k] = 0; }
}

// Fused layer: 16 nodes/wave; 4 edges/gather-instr (quarter-wave per edge,
// 4 features/lane). Pair-interleaved static 2x8 chunks, UNMASKED (segments
// zero-padded to x16 by binD2). Zero-degree nodes skipped via scalar guard.
#define NPW 16
#define WPB 2
#define NPB (NPW * WPB)                       // 32
#define LB2 ((N_NODES + NPB - 1) / NPB)       // 3125

__global__ __launch_bounds__(128, 8) void cheb_layer(const ushort* __restrict__ x,
                                                     const int* __restrict__ srcs,
                                                     const ushort* __restrict__ nrms,
                                                     const int* __restrict__ endp,
                                                     const int* __restrict__ cnt,
                                                     const ushort* __restrict__ pk,
                                                     const float* __restrict__ bias,
                                                     ushort* __restrict__ out_bf,
                                                     float* __restrict__ out_f32,
                                                     int last) {
    __shared__ ushort sA[WPB][16][136];   // 8.7 KB

    int t = threadIdx.x;
    int lane = t & 63, wid = t >> 6;
    int c = lane & 15, q = lane >> 4;
    int qd = q, fg = c;
    int nb = blockIdx.x * NPB + wid * NPW;

    int nend = 0, ncnt = 0;
    if (lane < NPW && nb + lane < N_NODES) {
        nend = endp[nb + lane];
        ncnt = cnt[nb + lane];
    }

    const uint2* xr = (const uint2*)x;   // row = 16 uint2 (64 bf16)

    auto chunk8 = [&](int eb, float& a0, float& a1, float& a2, float& a3) {
        int4 sv = *(const int4*)(srcs + eb);       // edges eb..eb+3 (uniform)
        int4 sw = *(const int4*)(srcs + eb + 4);   // edges eb+4..eb+7
        uint2 nv = *(const uint2*)(nrms + eb);
        uint2 nw = *(const uint2*)(nrms + eb + 4);
        int sA01 = (qd & 1) ? sv.y : sv.x;
        int sA23 = (qd & 1) ? sv.w : sv.z;
        int srcA = (qd & 2) ? sA23 : sA01;
        int sB01 = (qd & 1) ? sw.y : sw.x;
        int sB23 = (qd & 1) ? sw.w : sw.z;
        int srcB = (qd & 2) ? sB23 : sB01;
        uint nAp = (qd & 2) ? nv.y : nv.x;
        uint nBp = (qd & 2) ? nw.y : nw.x;
        float nAf = __uint_as_float((qd & 1) ? (nAp & 0xffff0000u) : (nAp << 16));
        float nBf = __uint_as_float((qd & 1) ? (nBp & 0xffff0000u) : (nBp << 16));
        uint2 gA = xr[(size_t)srcA * 16 + fg];
        uint2 gB = xr[(size_t)srcB * 16 + fg];
        a0 = fmaf(nAf, __uint_as_float(gA.x << 16), a0);
        a1 = fmaf(nAf, __uint_as_float(gA.x & 0xffff0000u), a1);
        a2 = fmaf(nAf, __uint_as_float(gA.y << 16), a2);
        a3 = fmaf(nAf, __uint_as_float(gA.y & 0xffff0000u), a3);
        a0 = fmaf(nBf, __uint_as_float(gB.x << 16), a0);
        a1 = fmaf(nBf, __uint_as_float(gB.x & 0xffff0000u), a1);
        a2 = fmaf(nBf, __uint_as_float(gB.y << 16), a2);
        a3 = fmaf(nBf, __uint_as_float(gB.y & 0xffff0000u), a3);
    };

    for (int gp = 0; gp < NPW; gp += 2) {
        int cn0 = __builtin_amdgcn_readlane(ncnt, gp);
        int ee0 = __builtin_amdgcn_readlane(nend, gp);
        int cn1 = __builtin_amdgcn_readlane(ncnt, gp + 1);
        int ee1 = __builtin_amdgcn_readlane(nend, gp + 1);
        int s0 = ee0 - cn0, s1 = ee1 - cn1;       // 16-aligned starts
        int ac0 = (cn0 + 15) & ~15;               // padded segment lengths
        int ac1 = (cn1 + 15) & ~15;
        float a0 = 0, a1 = 0, a2 = 0, a3 = 0;
        float b0 = 0, b1 = 0, b2 = 0, b3 = 0;

        // static 2x8-edge chunks per node, pair-interleaved, unmasked
        if (cn0) { chunk8(s0, a0, a1, a2, a3); }
        if (cn1) { chunk8(s1, b0, b1, b2, b3); }
        if (cn0) { chunk8(s0 + 8, a0, a1, a2, a3); }
        if (cn1) { chunk8(s1 + 8, b0, b1, b2, b3); }
        // rare heavy nodes (cn > 16); pads contribute zero
        for (int e = s0 + 16; e < s0 + ac0; e += 8) chunk8(e, a0, a1, a2, a3);
        for (int e = s1 + 16; e < s1 + ac1; e += 8) chunk8(e, b0, b1, b2, b3);

        // interleaved cross-quarter reductions for both nodes
        a0 += __shfl_xor(a0, 16, 64); b0 += __shfl_xor(b0, 16, 64);
        a1 += __shfl_xor(a1, 16, 64); b1 += __shfl_xor(b1, 16, 64);
        a2 += __shfl_xor(a2, 16, 64); b2 += __shfl_xor(b2, 16, 64);
        a3 += __shfl_xor(a3, 16, 64); b3 += __shfl_xor(b3, 16, 64);
        a0 += __shfl_xor(a0, 32, 64); b0 += __shfl_xor(b0, 32, 64);
        a1 += __shfl_xor(a1, 32, 64); b1 += __shfl_xor(b1, 32, 64);
        a2 += __shfl_xor(a2, 32, 64); b2 += __shfl_xor(b2, 32, 64);
        a3 += __shfl_xor(a3, 32, 64); b3 += __shfl_xor(b3, 32, 64);

        int node0 = nb + gp, node1 = nb + gp + 1;
        int ni0 = (node0 < N_NODES) ? node0 : 0;
        int ni1 = (node1 < N_NODES) ? node1 : 0;
        if (qd == 0) {
            uint2 xv0 = xr[(size_t)ni0 * 16 + fg];
            uint2 xv1 = xr[(size_t)ni1 * 16 + fg];
            *(uint2*)&sA[wid][gp][4 * fg] = xv0;
            *(uint2*)&sA[wid][gp + 1][4 * fg] = xv1;
        }
        if (qd == 1) {
            uint2 p0, p1;
            p0.x = (uint)f2bf(a0) | ((uint)f2bf(a1) << 16);
            p0.y = (uint)f2bf(a2) | ((uint)f2bf(a3) << 16);
            p1.x = (uint)f2bf(b0) | ((uint)f2bf(b1) << 16);
            p1.y = (uint)f2bf(b2) | ((uint)f2bf(b3) << 16);
            *(uint2*)&sA[wid][gp][64 + 4 * fg] = p0;
            *(uint2*)&sA[wid][gp + 1][64 + 4 * fg] = p1;
        }
    }
    __builtin_amdgcn_wave_barrier();

    const short8* pk8 = (const short8*)pk;
    float4v C[4];
#pragma unroll
    for (int nt = 0; nt < 4; ++nt) {
        float b = bias[nt * 16 + c];
        C[nt] = (float4v){b, b, b, b};
    }
#pragma unroll
    for (int kt = 0; kt < 4; ++kt) {
        short8 af = *(const short8*)&sA[wid][c][kt * 32 + q * 8];
#pragma unroll
        for (int nt = 0; nt < 4; ++nt) {
            short8 bfr = pk8[(kt * 4 + nt) * 64 + lane];
            C[nt] = __builtin_amdgcn_mfma_f32_16x16x32_bf16(af, bfr, C[nt], 0, 0, 0);
        }
    }

#pragma unroll
    for (int nt = 0; nt < 4; ++nt) {
#pragma unroll
        for (int i = 0; i < 4; ++i) {
            int node = nb + q * 4 + i;
            if (node < N_NODES) {
                float v = C[nt][i];
                if (!last) {
                    v = fmaxf(v, 0.0f);
                    out_bf[(size_t)node * NF + nt * 16 + c] = f2bf(v);
                } else {
                    out_f32[(size_t)node * NF + nt * 16 + c] = v;
                }
            }
        }
    }
}

extern "C" void kernel_launch(void* const* d_in, const int* in_sizes, int n_in,
                              void* d_out, int out_size, void* d_ws, size_t ws_size,
                              hipStream_t stream) {
    const int* ei = (const int*)d_in[0];
    const int* row = ei;
    const int* col = ei + N_EDGES;
    const float* emb = (const float*)d_in[1];
    const float* W1_0 = (const float*)d_in[2];
    const float* W1_1 = (const float*)d_in[3];
    const float* b1 = (const float*)d_in[4];
    const float* W2_0 = (const float*)d_in[5];
    const float* W2_1 = (const float*)d_in[6];
    const float* b2 = (const float*)d_in[7];
    float* out = (float*)d_out;

    char* ws = (char*)d_ws;
    int* cnt = (int*)(ws + OFF_CNT);
    int* endp = (int*)(ws + OFF_ENDP);
    float* dinv = (float*)(ws + OFF_DINV);
    int* cur = (int*)(ws + OFF_CUR);
    ushort* pk = (ushort*)(ws + OFF_PKW);
    int* srcs = (int*)(ws + OFF_SRCS);
    ushort* nrms = (ushort*)(ws + OFF_NRMS);
    ushort* sbinned = (ushort*)(ws + OFF_SBIN);
    int* dbinned = (int*)(ws + OFF_DBIN);
    ushort* emb_bf = (ushort*)(ws + OFF_EMBBF);
    ushort* h_bf = (ushort*)(ws + OFF_HBF);

    prep<<<9 + 3125, 256, 0, stream>>>(W1_0, W1_1, W2_0, W2_1, pk, cur, emb, emb_bf);
    binsort<<<NBLK, 256, 0, stream>>>(row, col, cur, sbinned, dbinned);
    binD1<<<NBINS, 512, 0, stream>>>(sbinned, cur, dinv);
    binD2<<<NBINS, 512, 0, stream>>>(dbinned, cur, dinv, cnt, endp, srcs, nrms);

    cheb_layer<<<LB2, 128, 0, stream>>>(emb_bf, srcs, nrms, endp, cnt, pk, b1, h_bf, nullptr, 0);
    cheb_layer<<<LB2, 128, 0, stream>>>(h_bf, srcs, nrms, endp, cnt, pk + 8192, b2, nullptr, out, 1);
}